// Round 10
// baseline (1152.350 us; speedup 1.0000x reference)
//
#include <hip/hip_runtime.h>
#include <math.h>

#define N_NODES 20000
#define E_EDGES 320000
#define EP (E_EDGES + N_NODES)   // 340000 edges incl. self-loops
#define D 256
#define NHEAD 4
#define CH 64
#define NEG_SLOPE 0.2f
#define LN_EPS 1e-5f

typedef _Float16 half8_t __attribute__((ext_vector_type(8)));
typedef _Float16 half4_t __attribute__((ext_vector_type(4)));
typedef _Float16 half2_t __attribute__((ext_vector_type(2)));
typedef float   float4_t __attribute__((ext_vector_type(4)));
typedef int     iv4_t    __attribute__((ext_vector_type(4)));

#define SCATTER_BLOCKS ((EP + 255) / 256)           // 1329
#define CONV_BLOCKS ((N_NODES * D / 4 + 255) / 256) // 5000
#define MEGA_GRID 768                                // 3 blocks/CU x 256 CU: all co-resident

__device__ __forceinline__ void async_cp16(const void* g, void* l)
{
    __builtin_amdgcn_global_load_lds(
        (const __attribute__((address_space(1))) void*)g,
        (__attribute__((address_space(3))) void*)l, 16, 0, 0);
}

// ---- DPP reductions (pure VALU, no LDS pipe) ----
template<int CTRL>
__device__ __forceinline__ float dpp_add(float v) {
    int t = __builtin_amdgcn_update_dpp(0, __float_as_int(v), CTRL, 0xF, 0xF, true);
    return v + __int_as_float(t);
}
// sum over each aligned 8-lane group (== one head at 8 ch/lane)
__device__ __forceinline__ float grp8_sum(float v) {
    v = dpp_add<0xB1>(v);    // quad_perm [1,0,3,2]  (xor 1)
    v = dpp_add<0x4E>(v);    // quad_perm [2,3,0,1]  (xor 2)
    v = dpp_add<0x141>(v);   // row_half_mirror      (crosses 4-group)
    return v;
}

// 16B index load, only 4B-aligned (start offsets are arbitrary)
__device__ __forceinline__ iv4_t load_idx4(const int* p) {
    iv4_t v;
    __builtin_memcpy(&v, p, 16);
    return v;
}

__device__ __forceinline__ float dot_att8(half8_t t, const half2_t a0, const half2_t a1,
                                          const half2_t a2, const half2_t a3) {
    half2_t t01 = {t[0], t[1]}, t23 = {t[2], t[3]};
    half2_t t45 = {t[4], t[5]}, t67 = {t[6], t[7]};
    float v = __builtin_amdgcn_fdot2(t01, a0, 0.0f, false);
    v = __builtin_amdgcn_fdot2(t23, a1, v, false);
    v = __builtin_amdgcn_fdot2(t45, a2, v, false);
    return __builtin_amdgcn_fdot2(t67, a3, v, false);
}

// ---- grid-wide software barrier (all MEGA_GRID blocks co-resident) ----
// Sense-reversing via generation counter. Agent-scope acq/rel + threadfence
// gives cross-XCD visibility of plain stores (G16). State owned in d_ws:
// bar[0] = arrival counter, bar[1] = generation; zeroed by convert_hist.
__device__ __forceinline__ void grid_barrier(int* bar)
{
    __syncthreads();
    if (threadIdx.x == 0) {
        __threadfence();   // publish this block's prior stores (L2 writeback)
        int gen = __hip_atomic_load(&bar[1], __ATOMIC_RELAXED, __HIP_MEMORY_SCOPE_AGENT);
        int arrived = __hip_atomic_fetch_add(&bar[0], 1, __ATOMIC_ACQ_REL,
                                             __HIP_MEMORY_SCOPE_AGENT) + 1;
        if (arrived == MEGA_GRID) {
            __hip_atomic_store(&bar[0], 0, __ATOMIC_RELAXED, __HIP_MEMORY_SCOPE_AGENT);
            __hip_atomic_store(&bar[1], gen + 1, __ATOMIC_RELEASE, __HIP_MEMORY_SCOPE_AGENT);
        } else {
            while (__hip_atomic_load(&bar[1], __ATOMIC_RELAXED,
                                     __HIP_MEMORY_SCOPE_AGENT) == gen)
                __builtin_amdgcn_s_sleep(2);
        }
        __threadfence();   // acquire: invalidate caches before reading others' data
    }
    __syncthreads();
}

struct WPtrs { const float* p[8]; };

// ===== one-time: convert x -> f16, histogram degrees, weight convert,
// AND zero the mega-kernel barrier state (runs before mega in stream order).
__global__ __launch_bounds__(256)
void convert_hist_kernel(const float* __restrict__ x, _Float16* __restrict__ h16,
                         const int* __restrict__ ei, int* __restrict__ deg,
                         WPtrs wp, _Float16* __restrict__ Wt_all,
                         int* __restrict__ bar)
{
    if (blockIdx.x == 0 && threadIdx.x < 4) bar[threadIdx.x] = 0;
    if (blockIdx.x >= CONV_BLOCKS) {
        // weight convert: 128 blocks mapped to (bx, by, z) = (4, 4, 8)
        __shared__ float tile[64][65];
        int bz = blockIdx.x - CONV_BLOCKS;
        int bxi = bz & 3, byi = (bz >> 2) & 3, z = bz >> 4;
        const float* W = wp.p[z];
        _Float16* out = Wt_all + (size_t)z * 65536;
        int bx = bxi * 64, by = byi * 64;
        int t = threadIdx.x;
        #pragma unroll
        for (int i = 0; i < 16; ++i) {
            int idx = t + i * 256;
            int kk = idx >> 6, nn = idx & 63;
            tile[kk][nn] = W[(by + kk) * 256 + bx + nn];
        }
        __syncthreads();
        #pragma unroll
        for (int i = 0; i < 16; ++i) {
            int idx = t + i * 256;
            int nn = idx >> 6, kk = idx & 63;
            out[(bx + nn) * 256 + by + kk] = (_Float16)tile[kk][nn];
        }
        return;
    }
    int i = blockIdx.x * 256 + threadIdx.x;
    if (i < EP) {
        int dst = (i < E_EDGES) ? ei[E_EDGES + i] : (i - E_EDGES);
        atomicAdd(&deg[dst], 1);
    }
    if (i >= N_NODES * D / 4) return;
    float4 v = reinterpret_cast<const float4*>(x)[i];
    half4_t o;
    o.x = (_Float16)v.x; o.y = (_Float16)v.y; o.z = (_Float16)v.z; o.w = (_Float16)v.w;
    reinterpret_cast<half4_t*>(h16)[i] = o;
}

// single-pass block scan, LDS-staged for coalesced global access.
__global__ __launch_bounds__(1024)
void csr_scan_kernel(const int* __restrict__ deg, int* __restrict__ rowptr,
                     int* __restrict__ cursor, int* __restrict__ csr_src)
{
    __shared__ int buf[5120];
    __shared__ int wsum[16];
    __shared__ int carry_s;
    int t = threadIdx.x, lane = t & 63, w = t >> 6;
    if (t == 0) carry_s = 0;
    if (t < 8) csr_src[EP + t] = 0;      // slack for masked tail over-reads

    for (int c = 0; c < 4; ++c) {
        int base = c * 5120;
        #pragma unroll
        for (int k = 0; k < 5; ++k) {
            int idx = base + k * 1024 + t;
            buf[k * 1024 + t] = (idx < N_NODES) ? deg[idx] : 0;
        }
        __syncthreads();
        int loc[5]; int s = 0;
        #pragma unroll
        for (int k = 0; k < 5; ++k) { loc[k] = buf[t * 5 + k]; s += loc[k]; }
        int x = s;
        #pragma unroll
        for (int o = 1; o < 64; o <<= 1) {
            int y = __shfl_up(x, o, 64);
            if (lane >= o) x += y;
        }
        if (lane == 63) wsum[w] = x;
        __syncthreads();
        if (t == 0) {
            int sa = carry_s;
            #pragma unroll
            for (int k = 0; k < 16; ++k) { int tmp = wsum[k]; wsum[k] = sa; sa += tmp; }
            carry_s = sa;
        }
        __syncthreads();
        int excl = wsum[w] + x - s;
        #pragma unroll
        for (int k = 0; k < 5; ++k) { buf[t * 5 + k] = excl; excl += loc[k]; }
        __syncthreads();
        #pragma unroll
        for (int k = 0; k < 5; ++k) {
            int idx = base + k * 1024 + t;
            if (idx < N_NODES) {
                int v = buf[k * 1024 + t];
                rowptr[idx] = v;
                cursor[idx] = v;
            }
        }
        __syncthreads();
    }
    if (t == 0) rowptr[N_NODES] = carry_s;
}

// ================= GEMM tile (device fn): measured-best champion body =================
#define BM 128
#define BN 128
#define BK 64
#define EPAD2 72   // epilogue LDS row stride in f16 (144 B)
__device__ static void gemm_tile(int b, const _Float16* __restrict__ A16,
                                 const _Float16* __restrict__ Wt,
                                 _Float16* __restrict__ X0, _Float16* __restrict__ X1)
{
    __shared__ __align__(1024) char smem[BM * BK * 2 + BN * BK * 2];   // 32768 B
    __syncthreads();   // LDS reuse guard (previous job of this block)

    const int pair = ((b >> 4) << 3) + (b & 7);
    const int z = (b >> 3) & 1;
    if (pair >= 314) return;          // block-uniform: safe after barrier
    const int yb = (pair >= 157) ? 1 : 0;
    const int xb = pair - yb * 157;

    const _Float16* W = Wt + z * 65536 + yb * (BN * 256);
    _Float16* X = z ? X1 : X0;
    const int row0 = xb * BM;
    const int col0 = yb * BN;

    _Float16 (*As)[BK] = reinterpret_cast<_Float16 (*)[BK]>(smem);
    _Float16 (*Bs)[BK] = reinterpret_cast<_Float16 (*)[BK]>(smem + BM * BK * 2);
    _Float16* As_flat = reinterpret_cast<_Float16*>(smem);
    _Float16* Bs_flat = reinterpret_cast<_Float16*>(smem + BM * BK * 2);
    _Float16* ep = reinterpret_cast<_Float16*>(smem);

    const int tid  = threadIdx.x;
    const int wave = tid >> 6, lane = tid & 63;
    const int wy = wave >> 1, wx = wave & 1;
    const int quad = lane >> 4, l16 = lane & 15;

    float4_t acc[4][4];
    #pragma unroll
    for (int i = 0; i < 4; ++i)
        #pragma unroll
        for (int j = 0; j < 4; ++j) acc[i][j] = (float4_t)0.0f;

    const int r_in  = lane >> 3;          // 0..7
    const int c_in  = (lane & 7) * 8;     // f16 offset within row: 0..56

    #pragma unroll
    for (int k0 = 0; k0 < 256; k0 += BK) {
        #pragma unroll
        for (int j = 0; j < 4; ++j) {
            int ia  = wave * 4 + j;
            int row = ia * 8 + r_in;
            int gra = row0 + row;
            gra = (gra < N_NODES) ? gra : (N_NODES - 1);   // clamp; garbage never stored
            async_cp16(A16 + (size_t)gra * 256 + k0 + c_in, As_flat + ia * 512);
            async_cp16(W   + (size_t)row * 256 + k0 + c_in, Bs_flat + ia * 512);
        }
        __syncthreads();

        #pragma unroll
        for (int s = 0; s < 2; ++s) {
            half8_t af[4], bf[4];
            #pragma unroll
            for (int i = 0; i < 4; ++i)
                af[i] = *reinterpret_cast<const half8_t*>(&As[wy * 64 + i * 16 + l16][s * 32 + quad * 8]);
            #pragma unroll
            for (int j = 0; j < 4; ++j)
                bf[j] = *reinterpret_cast<const half8_t*>(&Bs[wx * 64 + j * 16 + l16][s * 32 + quad * 8]);
            #pragma unroll
            for (int i = 0; i < 4; ++i)
                #pragma unroll
                for (int j = 0; j < 4; ++j)
                    acc[i][j] = __builtin_amdgcn_mfma_f32_16x16x32_f16(af[i], bf[j], acc[i][j], 0, 0, 0);
        }
        __syncthreads();
    }

    // ---- epilogue: per-wave LDS transpose, 4 chunks of 16 rows x 64 cols ----
    _Float16* epw = ep + wave * 16 * EPAD2;          // 4 x 2304 B, disjoint
    #pragma unroll
    for (int it = 0; it < 4; ++it) {
        #pragma unroll
        for (int j = 0; j < 4; ++j)
            #pragma unroll
            for (int r = 0; r < 4; ++r)
                epw[(quad * 4 + r) * EPAD2 + j * 16 + l16] = (_Float16)acc[it][j][r];
        #pragma unroll
        for (int p = 0; p < 2; ++p) {
            int row = p * 8 + (lane >> 3);           // 0..15
            int col = (lane & 7) * 8;                // 0..56
            int gr = row0 + wy * 64 + it * 16 + row;
            half8_t v = *reinterpret_cast<const half8_t*>(&epw[row * EPAD2 + col]);
            if (gr < N_NODES)
                *reinterpret_cast<half8_t*>(X + gr * 256 + col0 + wx * 64 + col) = v;
        }
    }
}

// ===== GAT 4-node group (device fn): measured-best champion body =====
__device__ static void gat4(int grp, const _Float16* __restrict__ xl,
                            const _Float16* __restrict__ xr,
                            const int* __restrict__ rowptr, const int* __restrict__ csr_src,
                            const float* __restrict__ att, const float* __restrict__ bias,
                            const float* __restrict__ g, const float* __restrict__ be,
                            float* __restrict__ out32, _Float16* __restrict__ out16,
                            int write32)
{
    const int tid = threadIdx.x;
    const int w = tid >> 6, lane = tid & 63;
    const int n = grp * 4 + w;
    const int hs  = lane >> 5;
    const int l32 = lane & 31;
    const int c0  = l32 * 8;
    const int start = rowptr[n], end = rowptr[n + 1];

    half8_t xrv = *reinterpret_cast<const half8_t*>(xr + (size_t)n * D + c0);
    half2_t at0, at1, at2, at3;
    {
        float4 a0 = *reinterpret_cast<const float4*>(att + c0);
        float4 a1 = *reinterpret_cast<const float4*>(att + c0 + 4);
        at0 = half2_t{(_Float16)a0.x, (_Float16)a0.y};
        at1 = half2_t{(_Float16)a0.z, (_Float16)a0.w};
        at2 = half2_t{(_Float16)a1.x, (_Float16)a1.y};
        at3 = half2_t{(_Float16)a1.z, (_Float16)a1.w};
    }
    const _Float16 slope = (_Float16)NEG_SLOPE;

    float den = 0.0f;
    float num[8];
    #pragma unroll
    for (int k = 0; k < 8; ++k) num[k] = 0.0f;

    int i = start;
    iv4_t nxt = load_idx4(csr_src + i + 4 * hs);
    for (; i + 8 <= end; i += 8) {
        iv4_t cur = nxt;
        half8_t h[4];
        #pragma unroll
        for (int j = 0; j < 4; ++j)
            h[j] = *reinterpret_cast<const half8_t*>(xl + (size_t)cur[j] * D + c0);
        nxt = load_idx4(csr_src + i + 8 + 4 * hs);
        float p[4];
        #pragma unroll
        for (int j = 0; j < 4; ++j) {
            half8_t t = h[j] + xrv;
            t = __builtin_elementwise_max(t, t * slope);
            p[j] = dot_att8(t, at0, at1, at2, at3);
        }
        #pragma unroll
        for (int j = 0; j < 4; ++j) p[j] = grp8_sum(p[j]);
        #pragma unroll
        for (int j = 0; j < 4; ++j) p[j] = __expf(p[j]);
        #pragma unroll
        for (int j = 0; j < 4; ++j) {
            den += p[j];
            #pragma unroll
            for (int k = 0; k < 8; ++k)
                num[k] = fmaf(p[j], (float)h[j][k], num[k]);
        }
    }
    if (i < end) {
        iv4_t cur = nxt;
        half8_t h[4];
        #pragma unroll
        for (int j = 0; j < 4; ++j)
            h[j] = *reinterpret_cast<const half8_t*>(xl + (size_t)cur[j] * D + c0);
        float p[4];
        #pragma unroll
        for (int j = 0; j < 4; ++j) {
            half8_t t = h[j] + xrv;
            t = __builtin_elementwise_max(t, t * slope);
            p[j] = dot_att8(t, at0, at1, at2, at3);
        }
        #pragma unroll
        for (int j = 0; j < 4; ++j) p[j] = grp8_sum(p[j]);
        #pragma unroll
        for (int j = 0; j < 4; ++j) {
            float pj = (i + 4 * hs + j < end) ? __expf(p[j]) : 0.0f;
            den += pj;
            #pragma unroll
            for (int k = 0; k < 8; ++k)
                num[k] = fmaf(pj, (float)h[j][k], num[k]);
        }
    }

    den += __shfl_xor(den, 32, 64);
    #pragma unroll
    for (int k = 0; k < 8; ++k) num[k] += __shfl_xor(num[k], 32, 64);

    float inv_den = 1.0f / den;
    float4 b0 = *reinterpret_cast<const float4*>(bias + c0);
    float4 b1 = *reinterpret_cast<const float4*>(bias + c0 + 4);
    float a[8];
    a[0] = fmaf(num[0], inv_den, b0.x);
    a[1] = fmaf(num[1], inv_den, b0.y);
    a[2] = fmaf(num[2], inv_den, b0.z);
    a[3] = fmaf(num[3], inv_den, b0.w);
    a[4] = fmaf(num[4], inv_den, b1.x);
    a[5] = fmaf(num[5], inv_den, b1.y);
    a[6] = fmaf(num[6], inv_den, b1.z);
    a[7] = fmaf(num[7], inv_den, b1.w);

    float wsum = 0.0f, wsq = 0.0f;
    #pragma unroll
    for (int k = 0; k < 8; ++k) { wsum += a[k]; wsq += a[k] * a[k]; }
    #pragma unroll
    for (int o = 1; o < 32; o <<= 1) {
        wsum += __shfl_xor(wsum, o, 64);
        wsq  += __shfl_xor(wsq,  o, 64);
    }
    float mu = wsum * (1.0f / 256.0f);
    float var = wsq * (1.0f / 256.0f) - mu * mu;
    float rstd = rsqrtf(var + LN_EPS);

    float4 g0 = *reinterpret_cast<const float4*>(g + c0);
    float4 g1 = *reinterpret_cast<const float4*>(g + c0 + 4);
    float4 e0 = *reinterpret_cast<const float4*>(be + c0);
    float4 e1 = *reinterpret_cast<const float4*>(be + c0 + 4);
    float o8[8];
    o8[0] = fmaxf((a[0] - mu) * rstd * g0.x + e0.x, 0.0f);
    o8[1] = fmaxf((a[1] - mu) * rstd * g0.y + e0.y, 0.0f);
    o8[2] = fmaxf((a[2] - mu) * rstd * g0.z + e0.z, 0.0f);
    o8[3] = fmaxf((a[3] - mu) * rstd * g0.w + e0.w, 0.0f);
    o8[4] = fmaxf((a[4] - mu) * rstd * g1.x + e1.x, 0.0f);
    o8[5] = fmaxf((a[5] - mu) * rstd * g1.y + e1.y, 0.0f);
    o8[6] = fmaxf((a[6] - mu) * rstd * g1.z + e1.z, 0.0f);
    o8[7] = fmaxf((a[7] - mu) * rstd * g1.w + e1.w, 0.0f);

    float s0 = hs ? o8[4] : o8[0];
    float s1 = hs ? o8[5] : o8[1];
    float s2 = hs ? o8[6] : o8[2];
    float s3 = hs ? o8[7] : o8[3];
    if (write32) {
        float4 ov = make_float4(s0, s1, s2, s3);
        *reinterpret_cast<float4*>(out32 + (size_t)n * D + c0 + 4 * hs) = ov;
    } else {
        half4_t ov;
        ov.x = (_Float16)s0; ov.y = (_Float16)s1; ov.z = (_Float16)s2; ov.w = (_Float16)s3;
        *reinterpret_cast<half4_t*>(out16 + (size_t)n * D + c0 + 4 * hs) = ov;
    }
}

// ===== mega-kernel: all 4 layers in ONE regular dispatch =====
// 768 blocks = 3/CU (LDS 96/160 KB, launch_bounds(256,3) caps VGPR at 170):
// all blocks co-resident by construction -> software grid barrier is
// deadlock-free. Regular (non-cooperative) launch -> graph-capture-safe;
// barrier state lives in d_ws (zeroed by convert_hist each call).
// Phase A(l): 640 gemm jobs (+1329 scatter chunks at l=0, needs only scan).
// Phase B(l): 5000 gat groups. 7 barriers replace 7 dispatch boundaries.
struct MegaParams {
    const _Float16* h16c; _Float16* h16;
    _Float16* xl; _Float16* xr;
    const _Float16* WtA;
    const int* rowptr; int* csr_src; int* cursor;
    const int* ei;
    const float* att[4]; const float* bias[4];
    const float* g[4];   const float* be[4];
    float* out32;
    int* bar;
};

__global__ __launch_bounds__(256, 3)
void mega_kernel(MegaParams p)
{
    #pragma unroll 1
    for (int l = 0; l < 4; ++l) {
        const _Float16* Wl = p.WtA + (size_t)l * 131072;
        const int njobs = (l == 0) ? (640 + SCATTER_BLOCKS) : 640;
        #pragma unroll 1
        for (int j = blockIdx.x; j < njobs; j += MEGA_GRID) {
            if (j < 640) {
                gemm_tile(j, p.h16c, Wl, p.xl, p.xr);
            } else {                       // CSR scatter chunk (layer 0 only)
                int e = (j - 640) * 256 + threadIdx.x;
                if (e < EP) {
                    int src, dst;
                    if (e < E_EDGES) { src = p.ei[e]; dst = p.ei[E_EDGES + e]; }
                    else             { src = dst = e - E_EDGES; }
                    int pos = atomicAdd(&p.cursor[dst], 1);
                    p.csr_src[pos] = src;
                }
            }
        }
        grid_barrier(p.bar);               // xl/xr (+csr_src at l=0) complete
        const int w32 = (l == 3) ? 1 : 0;
        #pragma unroll 1
        for (int grp = blockIdx.x; grp < N_NODES / 4; grp += MEGA_GRID)
            gat4(grp, p.xl, p.xr, p.rowptr, p.csr_src,
                 p.att[l], p.bias[l], p.g[l], p.be[l], p.out32, p.h16, w32);
        if (l < 3) grid_barrier(p.bar);    // h16 complete for next layer's GEMM
    }
}

// ================= launch =================
extern "C" void kernel_launch(void* const* d_in, const int* in_sizes, int n_in,
                              void* d_out, int out_size, void* d_ws, size_t ws_size,
                              hipStream_t stream)
{
    const float* x  = (const float*)d_in[0];
    const int*   ei = (const int*)d_in[1];

    char* ws = (char*)d_ws;
    size_t off = 0;
    _Float16* h16   = (_Float16*)(ws + off); off += (size_t)N_NODES * D * 2;      // 10.24 MB
    _Float16* xl    = (_Float16*)(ws + off); off += (size_t)N_NODES * D * 2;      // 10.24 MB
    _Float16* xr    = (_Float16*)(ws + off); off += (size_t)N_NODES * D * 2;      // 10.24 MB
    _Float16* WtA   = (_Float16*)(ws + off); off += (size_t)8 * 65536 * 2;        // 1 MB
    int* rowptr     = (int*)(ws + off);      off += (size_t)(N_NODES + 32) * 4;
    int* cursor     = (int*)(ws + off);      off += (size_t)N_NODES * 4;
    int* csr_src    = (int*)(ws + off);      off += (size_t)(EP + 32) * 4;
    int* bar        = (int*)(ws + off);      off += 64;

    WPtrs wp;
    for (int l = 0; l < 4; ++l) {
        wp.p[2 * l + 0] = (const float*)d_in[2 + 6 * l + 0];
        wp.p[2 * l + 1] = (const float*)d_in[2 + 6 * l + 1];
    }

    // setup: memset(deg) -> convert+hist+wconv+barzero -> scan -> MEGA
    hipMemsetAsync(cursor, 0, (size_t)N_NODES * 4, stream);          // deg = 0
    convert_hist_kernel<<<CONV_BLOCKS + 128, 256, 0, stream>>>(x, h16, ei, cursor,
                                                               wp, WtA, bar);
    csr_scan_kernel<<<1, 1024, 0, stream>>>(cursor, rowptr, cursor, csr_src);

    MegaParams mp;
    mp.h16c = h16; mp.h16 = h16; mp.xl = xl; mp.xr = xr; mp.WtA = WtA;
    mp.rowptr = rowptr; mp.csr_src = csr_src; mp.cursor = cursor; mp.ei = ei;
    for (int l = 0; l < 4; ++l) {
        mp.att[l]  = (const float*)d_in[2 + 6 * l + 2];
        mp.bias[l] = (const float*)d_in[2 + 6 * l + 3];
        mp.g[l]    = (const float*)d_in[2 + 6 * l + 4];
        mp.be[l]   = (const float*)d_in[2 + 6 * l + 5];
    }
    mp.out32 = (float*)d_out;
    mp.bar = bar;

    mega_kernel<<<MEGA_GRID, 256, 0, stream>>>(mp);
}

// Round 11
// 317.373 us; speedup vs baseline: 3.6309x; 3.6309x over previous
//
#include <hip/hip_runtime.h>
#include <math.h>

#define N_NODES 20000
#define E_EDGES 320000
#define EP (E_EDGES + N_NODES)   // 340000 edges incl. self-loops
#define D 256
#define NHEAD 4
#define CH 64
#define NEG_SLOPE 0.2f
#define LN_EPS 1e-5f

typedef _Float16 half8_t __attribute__((ext_vector_type(8)));
typedef _Float16 half4_t __attribute__((ext_vector_type(4)));
typedef _Float16 half2_t __attribute__((ext_vector_type(2)));
typedef float   float4_t __attribute__((ext_vector_type(4)));
typedef int     iv4_t    __attribute__((ext_vector_type(4)));

#define SCATTER_BLOCKS ((EP + 255) / 256)           // 1329
#define CONV_BLOCKS ((N_NODES * D / 4 + 255) / 256) // 5000

__device__ __forceinline__ void async_cp16(const void* g, void* l)
{
    __builtin_amdgcn_global_load_lds(
        (const __attribute__((address_space(1))) void*)g,
        (__attribute__((address_space(3))) void*)l, 16, 0, 0);
}

// ---- DPP reductions (pure VALU, no LDS pipe) ----
template<int CTRL>
__device__ __forceinline__ float dpp_add(float v) {
    int t = __builtin_amdgcn_update_dpp(0, __float_as_int(v), CTRL, 0xF, 0xF, true);
    return v + __int_as_float(t);
}
// sum over each aligned 8-lane group (== one head at 8 ch/lane)
__device__ __forceinline__ float grp8_sum(float v) {
    v = dpp_add<0xB1>(v);    // quad_perm [1,0,3,2]  (xor 1)
    v = dpp_add<0x4E>(v);    // quad_perm [2,3,0,1]  (xor 2)
    v = dpp_add<0x141>(v);   // row_half_mirror      (crosses 4-group)
    return v;
}

// 16B index load, only 4B-aligned (start offsets are arbitrary)
__device__ __forceinline__ iv4_t load_idx4(const int* p) {
    iv4_t v;
    __builtin_memcpy(&v, p, 16);
    return v;
}

__device__ __forceinline__ float dot_att8(half8_t t, const half2_t a0, const half2_t a1,
                                          const half2_t a2, const half2_t a3) {
    half2_t t01 = {t[0], t[1]}, t23 = {t[2], t[3]};
    half2_t t45 = {t[4], t[5]}, t67 = {t[6], t[7]};
    float v = __builtin_amdgcn_fdot2(t01, a0, 0.0f, false);
    v = __builtin_amdgcn_fdot2(t23, a1, v, false);
    v = __builtin_amdgcn_fdot2(t45, a2, v, false);
    return __builtin_amdgcn_fdot2(t67, a3, v, false);
}

struct WPtrs { const float* p[8]; };

// ===== one-time: convert x -> f16, histogram degrees, AND weight convert =====
// Grid = CONV_BLOCKS + 128. Blocks >= CONV_BLOCKS run the weight
// convert/transpose (depends only on d_in weights -> no need to wait behind
// the CSR chain). deg must be pre-zeroed via hipMemsetAsync.
__global__ __launch_bounds__(256)
void convert_hist_kernel(const float* __restrict__ x, _Float16* __restrict__ h16,
                         const int* __restrict__ ei, int* __restrict__ deg,
                         WPtrs wp, _Float16* __restrict__ Wt_all)
{
    if (blockIdx.x >= CONV_BLOCKS) {
        // weight convert: 128 blocks mapped to (bx, by, z) = (4, 4, 8)
        __shared__ float tile[64][65];
        int bz = blockIdx.x - CONV_BLOCKS;
        int bxi = bz & 3, byi = (bz >> 2) & 3, z = bz >> 4;
        const float* W = wp.p[z];
        _Float16* out = Wt_all + (size_t)z * 65536;
        int bx = bxi * 64, by = byi * 64;
        int t = threadIdx.x;
        #pragma unroll
        for (int i = 0; i < 16; ++i) {
            int idx = t + i * 256;
            int kk = idx >> 6, nn = idx & 63;
            tile[kk][nn] = W[(by + kk) * 256 + bx + nn];
        }
        __syncthreads();
        #pragma unroll
        for (int i = 0; i < 16; ++i) {
            int idx = t + i * 256;
            int nn = idx >> 6, kk = idx & 63;
            out[(bx + nn) * 256 + by + kk] = (_Float16)tile[kk][nn];
        }
        return;
    }
    int i = blockIdx.x * 256 + threadIdx.x;
    if (i < EP) {
        int dst = (i < E_EDGES) ? ei[E_EDGES + i] : (i - E_EDGES);
        atomicAdd(&deg[dst], 1);
    }
    if (i >= N_NODES * D / 4) return;
    float4 v = reinterpret_cast<const float4*>(x)[i];
    half4_t o;
    o.x = (_Float16)v.x; o.y = (_Float16)v.y; o.z = (_Float16)v.z; o.w = (_Float16)v.w;
    reinterpret_cast<half4_t*>(h16)[i] = o;
}

// single-pass block scan, LDS-staged for coalesced global access.
// 4 chunks of 5120 nodes; thread t owns 5 consecutive nodes per chunk.
__global__ __launch_bounds__(1024)
void csr_scan_kernel(const int* __restrict__ deg, int* __restrict__ rowptr,
                     int* __restrict__ cursor, int* __restrict__ csr_src)
{
    __shared__ int buf[5120];
    __shared__ int wsum[16];
    __shared__ int carry_s;
    int t = threadIdx.x, lane = t & 63, w = t >> 6;
    if (t == 0) carry_s = 0;
    if (t < 8) csr_src[EP + t] = 0;      // slack for masked tail over-reads

    for (int c = 0; c < 4; ++c) {
        int base = c * 5120;
        // coalesced load (stride-1 across lanes)
        #pragma unroll
        for (int k = 0; k < 5; ++k) {
            int idx = base + k * 1024 + t;
            buf[k * 1024 + t] = (idx < N_NODES) ? deg[idx] : 0;
        }
        __syncthreads();
        int loc[5]; int s = 0;
        #pragma unroll
        for (int k = 0; k < 5; ++k) { loc[k] = buf[t * 5 + k]; s += loc[k]; }
        int x = s;
        #pragma unroll
        for (int o = 1; o < 64; o <<= 1) {
            int y = __shfl_up(x, o, 64);
            if (lane >= o) x += y;
        }
        if (lane == 63) wsum[w] = x;
        __syncthreads();                  // also: all lanes done reading buf
        if (t == 0) {
            int sa = carry_s;
            #pragma unroll
            for (int k = 0; k < 16; ++k) { int tmp = wsum[k]; wsum[k] = sa; sa += tmp; }
            carry_s = sa;
        }
        __syncthreads();
        int excl = wsum[w] + x - s;
        #pragma unroll
        for (int k = 0; k < 5; ++k) { buf[t * 5 + k] = excl; excl += loc[k]; }
        __syncthreads();
        // coalesced store of rowptr and cursor
        #pragma unroll
        for (int k = 0; k < 5; ++k) {
            int idx = base + k * 1024 + t;
            if (idx < N_NODES) {
                int v = buf[k * 1024 + t];
                rowptr[idx] = v;
                cursor[idx] = v;
            }
        }
        __syncthreads();                  // buf reused next chunk
    }
    if (t == 0) rowptr[N_NODES] = carry_s;
}

// ================= GEMM: X = A16 @ W (f16 MFMA, fp32 accum, f16 out) =================
// A16: [M][256] f16 row-major; Wt: [256][256] f16 laid out [n][k].
// Blocks < 640: measured-best GEMM (XCD-pair-swizzled flat id; 12 idle).
// Blocks >= 640 (layer 0 only): CSR scatter -- independent of the GEMM work
// in this dispatch (needs only csr_scan's cursor), so it hides under the
// GEMM makespan and saves one dispatch boundary. gat (next dispatch) sees
// csr_src complete.
// BM=128, BN=128, BK=64. 4 waves as 2x2: wave (wy,wx) owns 64x64.
#define BM 128
#define BN 128
#define BK 64
#define EPAD2 72   // epilogue LDS row stride in f16 (144 B)
__global__ __launch_bounds__(256)
void gemm_f16_kernel(const _Float16* __restrict__ A16, const _Float16* __restrict__ Wt,
                     _Float16* __restrict__ X0, _Float16* __restrict__ X1, int nrows,
                     const int* __restrict__ ei, int* __restrict__ cursor,
                     int* __restrict__ csr_src)
{
    const int b = blockIdx.x;
    if (b >= 640) {                       // scatter blocks (layer-0 dispatch only)
        int e = (b - 640) * 256 + threadIdx.x;
        if (e >= EP) return;
        int src, dst;
        if (e < E_EDGES) { src = ei[e]; dst = ei[E_EDGES + e]; }
        else             { src = dst = e - E_EDGES; }
        int pos = atomicAdd(&cursor[dst], 1);
        csr_src[pos] = src;
        return;
    }

    // decode swizzled flat id: pair = (b>>4)*8 + (b&7), z = (b>>3)&1
    const int pair = ((b >> 4) << 3) + (b & 7);
    const int z = (b >> 3) & 1;
    if (pair >= 314) return;
    const int yb = (pair >= 157) ? 1 : 0;
    const int xb = pair - yb * 157;

    const _Float16* W = Wt + z * 65536 + yb * (BN * 256);
    _Float16* X = z ? X1 : X0;
    const int row0 = xb * BM;
    const int col0 = yb * BN;

    // staging: As 128x64 + Bs 128x64 f16 = 32 KB; epilogue reuses base region.
    __shared__ __align__(1024) char smem[BM * BK * 2 + BN * BK * 2];   // 32768 B
    _Float16 (*As)[BK] = reinterpret_cast<_Float16 (*)[BK]>(smem);
    _Float16 (*Bs)[BK] = reinterpret_cast<_Float16 (*)[BK]>(smem + BM * BK * 2);
    _Float16* As_flat = reinterpret_cast<_Float16*>(smem);
    _Float16* Bs_flat = reinterpret_cast<_Float16*>(smem + BM * BK * 2);
    _Float16* ep = reinterpret_cast<_Float16*>(smem);

    const int tid  = threadIdx.x;
    const int wave = tid >> 6, lane = tid & 63;
    const int wy = wave >> 1, wx = wave & 1;
    const int quad = lane >> 4, l16 = lane & 15;

    float4_t acc[4][4];
    #pragma unroll
    for (int i = 0; i < 4; ++i)
        #pragma unroll
        for (int j = 0; j < 4; ++j) acc[i][j] = (float4_t)0.0f;

    // staging geometry: each 1 KB instruction covers 8 rows of a 64-col f16
    // tile; lane l -> row +(l>>3), 16B chunk (l&7) within the 128 B row.
    const int r_in  = lane >> 3;          // 0..7
    const int c_in  = (lane & 7) * 8;     // f16 offset within row: 0..56

    #pragma unroll
    for (int k0 = 0; k0 < 256; k0 += BK) {
        // A: 16 instrs; wave w issues ia = 4w..4w+3.  B: same.
        #pragma unroll
        for (int j = 0; j < 4; ++j) {
            int ia  = wave * 4 + j;
            int row = ia * 8 + r_in;
            int gra = row0 + row;
            gra = (gra < nrows) ? gra : (nrows - 1);   // clamp; garbage rows never stored
            async_cp16(A16 + (size_t)gra * 256 + k0 + c_in, As_flat + ia * 512);
            async_cp16(W   + (size_t)row * 256 + k0 + c_in, Bs_flat + ia * 512);
        }
        __syncthreads();

        #pragma unroll
        for (int s = 0; s < 2; ++s) {
            half8_t af[4], bf[4];
            #pragma unroll
            for (int i = 0; i < 4; ++i)
                af[i] = *reinterpret_cast<const half8_t*>(&As[wy * 64 + i * 16 + l16][s * 32 + quad * 8]);
            #pragma unroll
            for (int j = 0; j < 4; ++j)
                bf[j] = *reinterpret_cast<const half8_t*>(&Bs[wx * 64 + j * 16 + l16][s * 32 + quad * 8]);
            #pragma unroll
            for (int i = 0; i < 4; ++i)
                #pragma unroll
                for (int j = 0; j < 4; ++j)
                    acc[i][j] = __builtin_amdgcn_mfma_f32_16x16x32_f16(af[i], bf[j], acc[i][j], 0, 0, 0);
        }
        __syncthreads();   // final barrier also protects epilogue LDS reuse
    }

    // ---- epilogue: per-wave LDS transpose, 4 chunks of 16 rows x 64 cols ----
    _Float16* epw = ep + wave * 16 * EPAD2;          // 4 x 2304 B, disjoint
    #pragma unroll
    for (int it = 0; it < 4; ++it) {
        #pragma unroll
        for (int j = 0; j < 4; ++j)
            #pragma unroll
            for (int r = 0; r < 4; ++r)
                epw[(quad * 4 + r) * EPAD2 + j * 16 + l16] = (_Float16)acc[it][j][r];
        // wave-internal dependency only: no barrier needed
        #pragma unroll
        for (int p = 0; p < 2; ++p) {
            int row = p * 8 + (lane >> 3);           // 0..15
            int col = (lane & 7) * 8;                // 0..56
            int gr = row0 + wy * 64 + it * 16 + row;
            half8_t v = *reinterpret_cast<const half8_t*>(&epw[row * EPAD2 + col]);
            if (gr < nrows)
                *reinterpret_cast<half8_t*>(X + gr * 256 + col0 + wx * 64 + col) = v;
        }
    }
}

// ===== fused GATv2 edge phase + LayerNorm + ReLU, one WAVE per node =====
// (measured-best body; occupancy-bound — needs full 32 waves/CU, per R10)
__global__ __launch_bounds__(256)
void gat_fused_kernel(const _Float16* __restrict__ xl, const _Float16* __restrict__ xr,
                      const int* __restrict__ rowptr, const int* __restrict__ csr_src,
                      const float* __restrict__ att,
                      const float* __restrict__ bias, const float* __restrict__ g,
                      const float* __restrict__ be,
                      float* __restrict__ out32, _Float16* __restrict__ out16,
                      int write32)
{
    const int tid = threadIdx.x;
    const int w = tid >> 6, lane = tid & 63;
    const int n = blockIdx.x * 4 + w;
    const int hs  = lane >> 5;           // which edge of the pair this half-wave owns
    const int l32 = lane & 31;
    const int c0  = l32 * 8;             // 8 channels per lane
    const int start = rowptr[n], end = rowptr[n + 1];

    half8_t xrv = *reinterpret_cast<const half8_t*>(xr + (size_t)n * D + c0);
    half2_t at0, at1, at2, at3;
    {
        float4 a0 = *reinterpret_cast<const float4*>(att + c0);
        float4 a1 = *reinterpret_cast<const float4*>(att + c0 + 4);
        at0 = half2_t{(_Float16)a0.x, (_Float16)a0.y};
        at1 = half2_t{(_Float16)a0.z, (_Float16)a0.w};
        at2 = half2_t{(_Float16)a1.x, (_Float16)a1.y};
        at3 = half2_t{(_Float16)a1.z, (_Float16)a1.w};
    }
    const _Float16 slope = (_Float16)NEG_SLOPE;

    float den = 0.0f;
    float num[8];
    #pragma unroll
    for (int k = 0; k < 8; ++k) num[k] = 0.0f;

    int i = start;
    iv4_t nxt = load_idx4(csr_src + i + 4 * hs);     // slack-safe: start+7 <= EP+7
    for (; i + 8 <= end; i += 8) {   // 8 edges (4 slots x 2 halves) in flight
        iv4_t cur = nxt;
        half8_t h[4];
        #pragma unroll
        for (int j = 0; j < 4; ++j)
            h[j] = *reinterpret_cast<const half8_t*>(xl + (size_t)cur[j] * D + c0);
        // prefetch next iteration's indices while gathers are in flight
        nxt = load_idx4(csr_src + i + 8 + 4 * hs);   // i+8 <= end -> offset <= EP+7
        float p[4];
        #pragma unroll
        for (int j = 0; j < 4; ++j) {
            half8_t t = h[j] + xrv;
            t = __builtin_elementwise_max(t, t * slope);
            p[j] = dot_att8(t, at0, at1, at2, at3);
        }
        #pragma unroll
        for (int j = 0; j < 4; ++j) p[j] = grp8_sum(p[j]);
        #pragma unroll
        for (int j = 0; j < 4; ++j) p[j] = __expf(p[j]);
        #pragma unroll
        for (int j = 0; j < 4; ++j) {
            den += p[j];
            #pragma unroll
            for (int k = 0; k < 8; ++k)
                num[k] = fmaf(p[j], (float)h[j][k], num[k]);
        }
    }
    if (i < end) {   // masked final iteration: 1..7 edges remain
        iv4_t cur = nxt;
        half8_t h[4];
        #pragma unroll
        for (int j = 0; j < 4; ++j)
            h[j] = *reinterpret_cast<const half8_t*>(xl + (size_t)cur[j] * D + c0);
        float p[4];
        #pragma unroll
        for (int j = 0; j < 4; ++j) {
            half8_t t = h[j] + xrv;
            t = __builtin_elementwise_max(t, t * slope);
            p[j] = dot_att8(t, at0, at1, at2, at3);
        }
        #pragma unroll
        for (int j = 0; j < 4; ++j) p[j] = grp8_sum(p[j]);
        #pragma unroll
        for (int j = 0; j < 4; ++j) {
            float pj = (i + 4 * hs + j < end) ? __expf(p[j]) : 0.0f;
            den += pj;
            #pragma unroll
            for (int k = 0; k < 8; ++k)
                num[k] = fmaf(pj, (float)h[j][k], num[k]);
        }
    }

    // merge the two half-wave partials (lanes l and l^32 hold same channels)
    den += __shfl_xor(den, 32, 64);
    #pragma unroll
    for (int k = 0; k < 8; ++k) num[k] += __shfl_xor(num[k], 32, 64);

    // normalize + bias (den is already per-head correct for this lane)
    float inv_den = 1.0f / den;
    float4 b0 = *reinterpret_cast<const float4*>(bias + c0);
    float4 b1 = *reinterpret_cast<const float4*>(bias + c0 + 4);
    float a[8];
    a[0] = fmaf(num[0], inv_den, b0.x);
    a[1] = fmaf(num[1], inv_den, b0.y);
    a[2] = fmaf(num[2], inv_den, b0.z);
    a[3] = fmaf(num[3], inv_den, b0.w);
    a[4] = fmaf(num[4], inv_den, b1.x);
    a[5] = fmaf(num[5], inv_den, b1.y);
    a[6] = fmaf(num[6], inv_den, b1.z);
    a[7] = fmaf(num[7], inv_den, b1.w);

    // LayerNorm over 256 channels: 8 in-lane partials + 5-step butterfly
    // (each 32-lane half independently covers all 256 channels after merge)
    float wsum = 0.0f, wsq = 0.0f;
    #pragma unroll
    for (int k = 0; k < 8; ++k) { wsum += a[k]; wsq += a[k] * a[k]; }
    #pragma unroll
    for (int o = 1; o < 32; o <<= 1) {
        wsum += __shfl_xor(wsum, o, 64);
        wsq  += __shfl_xor(wsq,  o, 64);
    }
    float mu = wsum * (1.0f / 256.0f);
    float var = wsq * (1.0f / 256.0f) - mu * mu;
    float rstd = rsqrtf(var + LN_EPS);

    float4 g0 = *reinterpret_cast<const float4*>(g + c0);
    float4 g1 = *reinterpret_cast<const float4*>(g + c0 + 4);
    float4 e0 = *reinterpret_cast<const float4*>(be + c0);
    float4 e1 = *reinterpret_cast<const float4*>(be + c0 + 4);
    float o8[8];
    o8[0] = fmaxf((a[0] - mu) * rstd * g0.x + e0.x, 0.0f);
    o8[1] = fmaxf((a[1] - mu) * rstd * g0.y + e0.y, 0.0f);
    o8[2] = fmaxf((a[2] - mu) * rstd * g0.z + e0.z, 0.0f);
    o8[3] = fmaxf((a[3] - mu) * rstd * g0.w + e0.w, 0.0f);
    o8[4] = fmaxf((a[4] - mu) * rstd * g1.x + e1.x, 0.0f);
    o8[5] = fmaxf((a[5] - mu) * rstd * g1.y + e1.y, 0.0f);
    o8[6] = fmaxf((a[6] - mu) * rstd * g1.z + e1.z, 0.0f);
    o8[7] = fmaxf((a[7] - mu) * rstd * g1.w + e1.w, 0.0f);

    // store: half 0 writes channels c0..c0+3, half 1 writes c0+4..c0+7
    // (constant indices + cndmask select -- no dynamic array indexing)
    float s0 = hs ? o8[4] : o8[0];
    float s1 = hs ? o8[5] : o8[1];
    float s2 = hs ? o8[6] : o8[2];
    float s3 = hs ? o8[7] : o8[3];
    if (write32) {
        float4 ov = make_float4(s0, s1, s2, s3);
        *reinterpret_cast<float4*>(out32 + (size_t)n * D + c0 + 4 * hs) = ov;
    } else {
        half4_t ov;
        ov.x = (_Float16)s0; ov.y = (_Float16)s1; ov.z = (_Float16)s2; ov.w = (_Float16)s3;
        *reinterpret_cast<half4_t*>(out16 + (size_t)n * D + c0 + 4 * hs) = ov;
    }
}

// ================= launch =================
extern "C" void kernel_launch(void* const* d_in, const int* in_sizes, int n_in,
                              void* d_out, int out_size, void* d_ws, size_t ws_size,
                              hipStream_t stream)
{
    const float* x  = (const float*)d_in[0];
    const int*   ei = (const int*)d_in[1];

    char* ws = (char*)d_ws;
    size_t off = 0;
    _Float16* h16   = (_Float16*)(ws + off); off += (size_t)N_NODES * D * 2;      // 10.24 MB
    _Float16* xl    = (_Float16*)(ws + off); off += (size_t)N_NODES * D * 2;      // 10.24 MB
    _Float16* xr    = (_Float16*)(ws + off); off += (size_t)N_NODES * D * 2;      // 10.24 MB
    _Float16* WtA   = (_Float16*)(ws + off); off += (size_t)8 * 65536 * 2;        // 1 MB
    int* rowptr     = (int*)(ws + off);      off += (size_t)(N_NODES + 32) * 4;
    int* cursor     = (int*)(ws + off);      off += (size_t)N_NODES * 4;
    int* csr_src    = (int*)(ws + off);      off += (size_t)(EP + 32) * 4;

    WPtrs wp;
    for (int l = 0; l < 4; ++l) {
        wp.p[2 * l + 0] = (const float*)d_in[2 + 6 * l + 0];
        wp.p[2 * l + 1] = (const float*)d_in[2 + 6 * l + 1];
    }

    // one-time per call: memset(deg) -> convert+hist+wconv -> scan
    // (CSR scatter rides inside the layer-0 GEMM dispatch)
    hipMemsetAsync(cursor, 0, (size_t)N_NODES * 4, stream);          // deg = 0
    convert_hist_kernel<<<CONV_BLOCKS + 128, 256, 0, stream>>>(x, h16, ei, cursor,
                                                               wp, WtA);
    csr_scan_kernel<<<1, 1024, 0, stream>>>(cursor, rowptr, cursor, csr_src);

    for (int l = 0; l < 4; ++l) {
        const float* att  = (const float*)d_in[2 + 6 * l + 2];
        const float* bias = (const float*)d_in[2 + 6 * l + 3];
        const float* g    = (const float*)d_in[2 + 6 * l + 4];
        const float* be   = (const float*)d_in[2 + 6 * l + 5];

        const int grid = (l == 0) ? (640 + SCATTER_BLOCKS) : 640;
        gemm_f16_kernel<<<grid, 256, 0, stream>>>(h16, WtA + (size_t)l * 131072,
                                                  xl, xr, N_NODES,
                                                  ei, cursor, csr_src);
        gat_fused_kernel<<<N_NODES / 4, 256, 0, stream>>>(xl, xr, rowptr, csr_src, att,
                                                          bias, g, be,
                                                          (float*)d_out, h16, (l == 3) ? 1 : 0);
    }
}